// Round 17
// baseline (41.917 us; speedup 1.0000x reference)
//
#include <hip/hip_runtime.h>
#include <math.h>

#define NROWS 8192
#define DIN   256
#define NH    8
#define NC    128
#define DOUT  256

typedef unsigned short ushort_t;
typedef __attribute__((ext_vector_type(8))) short bf16x8;
typedef __attribute__((ext_vector_type(4))) float f32x4;
typedef __attribute__((ext_vector_type(8))) unsigned short u16x8;

static __device__ __forceinline__ ushort_t f2bf(float f) {
  union { float f; unsigned u; } v; v.f = f;
  unsigned r = v.u + 0x7fffu + ((v.u >> 16) & 1u);
  return (ushort_t)(r >> 16);
}
static __device__ __forceinline__ float bf2f(ushort_t h) {
  union { unsigned u; float f; } v; v.u = ((unsigned)h) << 16;
  return v.f;
}

#define MFMA16(a, b, c) __builtin_amdgcn_mfma_f32_16x16x32_bf16((a), (b), (c), 0, 0, 0)
#define GLOAD_LDS16(g, l)                                                     \
  __builtin_amdgcn_global_load_lds(                                           \
      (const __attribute__((address_space(1))) void*)(g),                     \
      (__attribute__((address_space(3))) void*)(l), 16, 0, 0)

// ---------------------------------------------------------------------------
// Merged prep v2 (grid 544 x 256):
//  [0,16):    Wq transpose via LDS tile (k-tile 16): coalesced float4 reads,
//             32B-contiguous writes per wcvtT row. Values = f2bf (unchanged).
//  [16,32):   Wo transpose via LDS tile (k-tile 32): 64B writes per WoT row.
//  [32,288):  ctrs -> ctr3T + cbias (as before).
//  [288,544): Wv/Ov -> W2bT (as before, unroll 16).
// ---------------------------------------------------------------------------
__global__ __launch_bounds__(256) void prep_kernel(
    const float* __restrict__ Wq, const float* __restrict__ ctrs,
    const float* __restrict__ Wo, const float* __restrict__ Wv,
    const float* __restrict__ Ov, ushort_t* __restrict__ wcvtT,
    ushort_t* __restrict__ ctr3T, float* __restrict__ cbias,
    ushort_t* __restrict__ WoT, ushort_t* __restrict__ W2bT) {
  __shared__ __align__(16) char prep_lds[16 * 513 * 4];   // 32.8 KB union
  int bid = blockIdx.x;
  int t = threadIdx.x;
  if (bid < 16) {
    // ---- Wq: [256k][64p][8h] -> wcvtT[j=h*64+p][512] = [hi(256k)|lo(256k)]
    int k0 = bid * 16;
    unsigned* ldsq = (unsigned*)prep_lds;       // [16][513] packed hi|lo<<16
    #pragma unroll
    for (int i = 0; i < 8; ++i) {
      int f4 = i * 256 + t;                     // 0..2047 float4s
      int kk = f4 >> 7;                         // 128 float4 per k-row
      int q4 = (f4 & 127) << 2;                 // q = p*8+h
      float4 v = *(const float4*)(Wq + (((size_t)(k0 + kk)) << 9) + q4);
      float f[4] = {v.x, v.y, v.z, v.w};
      #pragma unroll
      for (int e = 0; e < 4; ++e) {
        ushort_t hi = f2bf(f[e]);
        ushort_t lo = f2bf(f[e] - bf2f(hi));
        ldsq[kk * 513 + q4 + e] = (unsigned)hi | ((unsigned)lo << 16);
      }
    }
    __syncthreads();
    #pragma unroll
    for (int jj = 0; jj < 2; ++jj) {
      int j = t * 2 + jj;                       // 0..511
      int h = j >> 6, p = j & 63;
      int q = p * 8 + h;
      unsigned pk[16];
      #pragma unroll
      for (int kk = 0; kk < 16; ++kk) pk[kk] = ldsq[kk * 513 + q];
      unsigned hw[8], lw[8];
      #pragma unroll
      for (int i2 = 0; i2 < 8; ++i2) {
        hw[i2] = (pk[2 * i2] & 0xffffu) | ((pk[2 * i2 + 1] & 0xffffu) << 16);
        lw[i2] = (pk[2 * i2] >> 16) | (pk[2 * i2 + 1] & 0xffff0000u);
      }
      *(uint4*)(wcvtT + (size_t)j * 512 + k0) =
          make_uint4(hw[0], hw[1], hw[2], hw[3]);
      *(uint4*)(wcvtT + (size_t)j * 512 + k0 + 8) =
          make_uint4(hw[4], hw[5], hw[6], hw[7]);
      *(uint4*)(wcvtT + (size_t)j * 512 + 256 + k0) =
          make_uint4(lw[0], lw[1], lw[2], lw[3]);
      *(uint4*)(wcvtT + (size_t)j * 512 + 256 + k0 + 8) =
          make_uint4(lw[4], lw[5], lw[6], lw[7]);
    }
  } else if (bid < 32) {
    // ---- Wo: [512k][256n] -> WoT[n][512k] (bf16), k-tile 32
    int k0 = (bid - 16) * 32;
    ushort_t* ldso = (ushort_t*)prep_lds;       // [32][257]
    #pragma unroll
    for (int i = 0; i < 8; ++i) {
      int f4 = i * 256 + t;                     // 0..2047 float4s
      int kk = f4 >> 6;                         // 64 float4 per k-row
      int n4 = (f4 & 63) << 2;
      float4 v = *(const float4*)(Wo + (((size_t)(k0 + kk)) << 8) + n4);
      float f[4] = {v.x, v.y, v.z, v.w};
      #pragma unroll
      for (int e = 0; e < 4; ++e) ldso[kk * 257 + n4 + e] = f2bf(f[e]);
    }
    __syncthreads();
    {
      int n = t;
      ushort_t row[32];
      #pragma unroll
      for (int kk = 0; kk < 32; ++kk) row[kk] = ldso[kk * 257 + n];
      unsigned wv4[16];
      #pragma unroll
      for (int i2 = 0; i2 < 16; ++i2)
        wv4[i2] = (unsigned)row[2 * i2] | ((unsigned)row[2 * i2 + 1] << 16);
      #pragma unroll
      for (int s4 = 0; s4 < 4; ++s4)
        *(uint4*)(WoT + (size_t)n * 512 + k0 + s4 * 8) =
            make_uint4(wv4[s4 * 4], wv4[s4 * 4 + 1], wv4[s4 * 4 + 2],
                       wv4[s4 * 4 + 3]);
    }
  } else if (bid < 288) {
    int idx = (bid - 32) * 4 + (t >> 6);   // h*128+c
    int p = t & 63;
    float v = ctrs[(size_t)idx * 64 + p];
    float sq = v * v;
    #pragma unroll
    for (int off = 32; off >= 1; off >>= 1) sq += __shfl_xor(sq, off, 64);
    if (p == 0) cbias[idx] = -sq;
    ushort_t hi = f2bf(v), lo = f2bf(v - bf2f(hi));
    ctr3T[(size_t)idx * 192 + p]       = hi;
    ctr3T[(size_t)idx * 192 + 64 + p]  = lo;
    ctr3T[(size_t)idx * 192 + 128 + p] = hi;
  } else {
    int b = (bid - 288) * 4 + (t >> 6);   // h*128 + c
    int p = t & 63;
    int h = b >> 7, c = b & 127;
    const float* wv = Wv + (size_t)b * 4096;
    float acc = 0.f;
    #pragma unroll 16
    for (int g = 0; g < 64; ++g) acc += wv[g * 64 + p];
    W2bT[((size_t)h * 128 + p) * 128 + c]      = f2bf(acc);
    W2bT[((size_t)h * 128 + 64 + p) * 128 + c] = f2bf(Ov[(size_t)b * 64 + p]);
  }
}

// ---------------------------------------------------------------------------
// gemm2 — byte-identical to r15 (BM=32, 1024 blocks, 4/CU).
// ---------------------------------------------------------------------------
__global__ __launch_bounds__(256) void gemm2_kernel(
    const ushort_t* __restrict__ A, const ushort_t* __restrict__ Bt,
    float* __restrict__ out) {
  __shared__ ushort_t At[32 * 64];
  __shared__ ushort_t Bl[64 * 64];
  const int t = threadIdx.x;
  const int w = t >> 6, l = t & 63;
  const int wr = w >> 1, wc = w & 1;
  const int m0 = (blockIdx.x >> 2) * 32, n0 = (blockIdx.x & 3) * 64;
  const int lr = l & 15, lk = l >> 4;

  f32x4 acc[2];
  #pragma unroll
  for (int b = 0; b < 2; ++b) acc[b] = (f32x4){0.f, 0.f, 0.f, 0.f};

  for (int k0 = 0; k0 < 512; k0 += 64) {
    {
      int q = w * 64 + l;
      int row = q >> 3, s = q & 7;
      int kl = k0 + ((s ^ (row & 7)) << 3);
      GLOAD_LDS16(A + (size_t)(m0 + row) * 512 + kl,
                  (char*)At + (size_t)w * 1024);
    }
    #pragma unroll
    for (int i = 0; i < 2; ++i) {
      int q = (i * 4 + w) * 64 + l;
      int row = q >> 3, s = q & 7;
      int kl = k0 + ((s ^ (row & 7)) << 3);
      GLOAD_LDS16(Bt + (size_t)(n0 + row) * 512 + kl,
                  (char*)Bl + (size_t)(i * 4 + w) * 1024);
    }
    __syncthreads();
    #pragma unroll
    for (int kk = 0; kk < 2; ++kk) {
      int rowa = wr * 16 + lr;
      int sa = (kk * 4 + lk) ^ (rowa & 7);
      bf16x8 af = *(const bf16x8*)((const char*)At + rowa * 128 + sa * 16);
      #pragma unroll
      for (int b = 0; b < 2; ++b) {
        int row = wc * 32 + b * 16 + lr;
        int s = (kk * 4 + lk) ^ (row & 7);
        bf16x8 bfr = *(const bf16x8*)((const char*)Bl + row * 128 + s * 16);
        acc[b] = MFMA16(af, bfr, acc[b]);
      }
    }
    __syncthreads();
  }
  #pragma unroll
  for (int b = 0; b < 2; ++b) {
    #pragma unroll
    for (int r = 0; r < 4; ++r) {
      int rowg = m0 + wr * 16 + lk * 4 + r;
      int colg = n0 + wc * 32 + b * 16 + lr;
      out[(size_t)rowg * 256 + colg] = acc[b][r];
    }
  }
}

// ---------------------------------------------------------------------------
// Fused-pair v3 — byte-identical to r15 (proven 41.0 µs path).
// ---------------------------------------------------------------------------
__global__ __launch_bounds__(256, 2) void fused_pair_kernel(
    const float* __restrict__ x,          // [8192][256] f32
    const ushort_t* __restrict__ wcvtT,   // [512][512] hi|lo
    const ushort_t* __restrict__ ctr3T,   // [1024][192]
    const float* __restrict__ cbias,      // [1024]
    const ushort_t* __restrict__ W2bT,    // [1024][128]
    ushort_t* __restrict__ ho2) {         // flat (h,N,p)
  __shared__ __align__(16) char Au_raw[36864];
  __shared__ char B0lds[16384];
  __shared__ char B1lds[16384];
  __shared__ float cb_lds[128];

  ushort_t* Axh = (ushort_t*)Au_raw;             // [128][72]
  ushort_t* Axl = (ushort_t*)(Au_raw + 18432);   // [128][72]
  ushort_t* A1  = (ushort_t*)Au_raw;             // [128][136]
  ushort_t* A2  = (ushort_t*)Au_raw;             // [128][136]

  const int t = threadIdx.x;
  const int w = t >> 6, l = t & 63;
  const int lr = l & 15, lk = l >> 4;
  const int h = blockIdx.x >> 6;                 // 8 heads x 64 pairs
  const int n0 = (blockIdx.x & 63) * 128;

#define STAGE_B(BUF, SRC, LDB, KOFF)                                          \
  {                                                                           \
    _Pragma("unroll")                                                         \
    for (int i = 0; i < 4; ++i) {                                             \
      int q = (i * 4 + w) * 64 + l;                                           \
      int row = q >> 3, s = q & 7;                                            \
      GLOAD_LDS16((SRC) + (size_t)(h * 128 + row) * (LDB) + (KOFF) +          \
                      ((s ^ (row & 7)) << 3),                                 \
                  (char*)(BUF) + (size_t)(i * 4 + w) * 1024);                 \
    }                                                                         \
  }

#define STAGE_BX(BUF, KC)                                                     \
  {                                                                           \
    _Pragma("unroll")                                                         \
    for (int i = 0; i < 4; ++i) {                                             \
      int q = (i * 4 + w) * 64 + l;                                           \
      int row = q >> 3, s = q & 7;                                            \
      int sw = (s ^ (row & 7)) << 3;                                          \
      int jj = h * 64 + (row & 63);                                           \
      int koff = (row < 64 ? 0 : 256) + (KC) * 64 + sw;                       \
      GLOAD_LDS16(wcvtT + (size_t)jj * 512 + koff,                            \
                  (char*)(BUF) + (size_t)(i * 4 + w) * 1024);                 \
    }                                                                         \
  }

#define MFMA_STEP(BUF, ACC0, ACC1, KBASE, ASPLIT)                             \
  {                                                                           \
    _Pragma("unroll")                                                         \
    for (int kk = 0; kk < 2; ++kk) {                                          \
      int klog = (KBASE) + kk * 32 + lk * 8;                                  \
      int kp = (ASPLIT) ? (klog < 64 ? klog : klog - 64) : klog;              \
      bf16x8 af0 = *(const bf16x8*)&A1[(w * 16 + lr) * 136 + kp];             \
      bf16x8 af1 = *(const bf16x8*)&A1[(64 + w * 16 + lr) * 136 + kp];        \
      _Pragma("unroll")                                                       \
      for (int cj = 0; cj < 8; ++cj) {                                        \
        int brow = cj * 16 + lr;                                              \
        int slot = (kk * 4 + lk) ^ (brow & 7);                                \
        bf16x8 bfr =                                                          \
            *(const bf16x8*)((const char*)(BUF) + brow * 128 + slot * 16);    \
        (ACC0)[cj] = MFMA16(af0, bfr, (ACC0)[cj]);                            \
        (ACC1)[cj] = MFMA16(af1, bfr, (ACC1)[cj]);                            \
      }                                                                       \
    }                                                                         \
  }

#define MFMAX(BUF)                                                            \
  {                                                                           \
    _Pragma("unroll")                                                         \
    for (int kk = 0; kk < 2; ++kk) {                                          \
      bf16x8 ah0 = *(const bf16x8*)&Axh[(w * 16 + lr) * 72 + kk * 32 + lk * 8];     \
      bf16x8 al0 = *(const bf16x8*)&Axl[(w * 16 + lr) * 72 + kk * 32 + lk * 8];     \
      bf16x8 ah1 = *(const bf16x8*)&Axh[(64 + w * 16 + lr) * 72 + kk * 32 + lk * 8];\
      bf16x8 al1 = *(const bf16x8*)&Axl[(64 + w * 16 + lr) * 72 + kk * 32 + lk * 8];\
      _Pragma("unroll")                                                       \
      for (int cj = 0; cj < 4; ++cj) {                                        \
        int rh = cj * 16 + lr;                                                \
        int slot = (kk * 4 + lk) ^ (rh & 7);                                  \
        bf16x8 bh = *(const bf16x8*)((const char*)(BUF) + rh * 128 + slot * 16);\
        bf16x8 bl = *(const bf16x8*)((const char*)(BUF) + (64 + rh) * 128 + slot * 16);\
        acc_x0[cj] = MFMA16(ah0, bh, acc_x0[cj]);                             \
        acc_x0[cj] = MFMA16(al0, bh, acc_x0[cj]);                             \
        acc_x0[cj] = MFMA16(ah0, bl, acc_x0[cj]);                             \
        acc_x1[cj] = MFMA16(ah1, bh, acc_x1[cj]);                             \
        acc_x1[cj] = MFMA16(al1, bh, acc_x1[cj]);                             \
        acc_x1[cj] = MFMA16(ah1, bl, acc_x1[cj]);                             \
      }                                                                       \
    }                                                                         \
  }

#define BAR() __builtin_amdgcn_s_barrier()
#define SCHED() __builtin_amdgcn_sched_barrier(0)
#define WAITALL_BAR()                                                         \
  {                                                                           \
    asm volatile("s_waitcnt vmcnt(0) lgkmcnt(0)" ::: "memory");               \
    SCHED(); BAR(); SCHED();                                                  \
  }

  const int xrow = t >> 2;                 // 0..63
  const int xseg = (t & 3) << 4;           // 0/16/32/48
  const float* xb0 = x + (size_t)(n0 + xrow) * 256 + xseg;
  const float* xb1 = xb0 + 64 * 256;
  float4 xr[8];

#define LOAD_X(KC)                                                            \
  {                                                                           \
    _Pragma("unroll")                                                         \
    for (int j = 0; j < 4; ++j) xr[j]     = *(const float4*)(xb0 + (KC) * 64 + j * 4); \
    _Pragma("unroll")                                                         \
    for (int j = 0; j < 4; ++j) xr[4 + j] = *(const float4*)(xb1 + (KC) * 64 + j * 4); \
  }

#define CVT_AX()                                                              \
  {                                                                           \
    _Pragma("unroll")                                                         \
    for (int hf = 0; hf < 2; ++hf) {                                          \
      u16x8 hv0, hv1, lv0, lv1;                                               \
      _Pragma("unroll")                                                       \
      for (int j = 0; j < 2; ++j) {                                           \
        float f4[8] = {xr[hf*4 + j*2].x, xr[hf*4 + j*2].y, xr[hf*4 + j*2].z,  \
                       xr[hf*4 + j*2].w, xr[hf*4 + j*2 + 1].x,                \
                       xr[hf*4 + j*2 + 1].y, xr[hf*4 + j*2 + 1].z,            \
                       xr[hf*4 + j*2 + 1].w};                                 \
        _Pragma("unroll")                                                     \
        for (int e = 0; e < 8; ++e) {                                         \
          ushort_t hi = f2bf(f4[e]);                                          \
          if (j == 0) { hv0[e] = hi; lv0[e] = f2bf(f4[e] - bf2f(hi)); }       \
          else        { hv1[e] = hi; lv1[e] = f2bf(f4[e] - bf2f(hi)); }       \
        }                                                                     \
      }                                                                       \
      int ro = hf * 64 + xrow;                                                \
      *(u16x8*)&Axh[ro * 72 + xseg]     = hv0;                                \
      *(u16x8*)&Axh[ro * 72 + xseg + 8] = hv1;                                \
      *(u16x8*)&Axl[ro * 72 + xseg]     = lv0;                                \
      *(u16x8*)&Axl[ro * 72 + xseg + 8] = lv1;                                \
    }                                                                         \
  }

#define SOFTMAX(ACC, ROFF)                                                    \
  {                                                                           \
    float cbv[8];                                                             \
    _Pragma("unroll")                                                         \
    for (int cj = 0; cj < 8; ++cj) cbv[cj] = cb_lds[cj * 16 + lr];            \
    _Pragma("unroll")                                                         \
    for (int r = 0; r < 4; ++r) {                                             \
      float v[8];                                                             \
      float m = -1e30f;                                                       \
      _Pragma("unroll")                                                       \
      for (int cj = 0; cj < 8; ++cj) {                                        \
        v[cj] = 2.f * (ACC)[cj][r] + cbv[cj];                                 \
        m = fmaxf(m, v[cj]);                                                  \
      }                                                                       \
      m = fmaxf(m, __shfl_xor(m, 1, 64));                                     \
      m = fmaxf(m, __shfl_xor(m, 2, 64));                                     \
      m = fmaxf(m, __shfl_xor(m, 4, 64));                                     \
      m = fmaxf(m, __shfl_xor(m, 8, 64));                                     \
      float s = 0.f;                                                          \
      _Pragma("unroll")                                                       \
      for (int cj = 0; cj < 8; ++cj) {                                        \
        v[cj] = __expf(v[cj] - m);                                            \
        s += v[cj];                                                           \
      }                                                                       \
      s += __shfl_xor(s, 1, 64);                                              \
      s += __shfl_xor(s, 2, 64);                                              \
      s += __shfl_xor(s, 4, 64);                                              \
      s += __shfl_xor(s, 8, 64);                                              \
      float inv = 1.f / s;                                                    \
      int row = (ROFF) + w * 16 + lk * 4 + r;                                 \
      _Pragma("unroll")                                                       \
      for (int cj = 0; cj < 8; ++cj)                                          \
        A2[row * 136 + cj * 16 + lr] = f2bf(v[cj] * inv);                     \
    }                                                                         \
  }

  // ---- Prologue: stage B(chunk0); x0 -> Ax ----
  cb_lds[t & 127] = cbias[h * 128 + (t & 127)];
  STAGE_BX(B0lds, 0);
  LOAD_X(0);
  f32x4 acc_x0[4], acc_x1[4];
  #pragma unroll
  for (int cj = 0; cj < 4; ++cj) {
    acc_x0[cj] = (f32x4){0.f, 0.f, 0.f, 0.f};
    acc_x1[cj] = (f32x4){0.f, 0.f, 0.f, 0.f};
  }
  CVT_AX();                                // chunk0 -> Ax (wave-local)
  WAITALL_BAR();                           // B0 ready

  // ---- R0 (chunk 0) ----
  STAGE_BX(B1lds, 1);
  LOAD_X(1);
  MFMAX(B0lds);
  CVT_AX();                                // chunk1 -> Ax (after own reads)
  WAITALL_BAR();
  // ---- R1 (chunk 1) ----
  STAGE_BX(B0lds, 2);
  LOAD_X(2);
  MFMAX(B1lds);
  CVT_AX();
  WAITALL_BAR();
  // ---- R2 (chunk 2) ----
  STAGE_BX(B1lds, 3);
  LOAD_X(3);
  MFMAX(B0lds);
  CVT_AX();
  WAITALL_BAR();
  // ---- R3 (chunk 3) ----
  STAGE_B(B0lds, ctr3T, 192, 0);
  MFMAX(B1lds);
  WAITALL_BAR();                           // Ax dead for ALL waves after this

  // ---- R4 (L0): write A1 from acc_x (wave-local), logits k 0..63 ----
  STAGE_B(B1lds, ctr3T, 192, 64);
  #pragma unroll
  for (int cj = 0; cj < 4; ++cj) {
    #pragma unroll
    for (int r = 0; r < 4; ++r) {
      int row = w * 16 + lk * 4 + r;
      int p = cj * 16 + lr;
      float v0 = acc_x0[cj][r];
      ushort_t hi0 = f2bf(v0);
      A1[row * 136 + p] = hi0;
      A1[row * 136 + 64 + p] = f2bf(v0 - bf2f(hi0));
      float v1 = acc_x1[cj][r];
      ushort_t hi1 = f2bf(v1);
      A1[(64 + row) * 136 + p] = hi1;
      A1[(64 + row) * 136 + 64 + p] = f2bf(v1 - bf2f(hi1));
    }
  }
  f32x4 acc0[8], acc1[8];
  #pragma unroll
  for (int cj = 0; cj < 8; ++cj) {
    acc0[cj] = (f32x4){0.f, 0.f, 0.f, 0.f};
    acc1[cj] = (f32x4){0.f, 0.f, 0.f, 0.f};
  }
  MFMA_STEP(B0lds, acc0, acc1, 0, 1);      // L0 (A1 same-wave, in-order DS)
  WAITALL_BAR();
  // ---- R5 (L1) ----
  STAGE_B(B0lds, ctr3T, 192, 128);
  MFMA_STEP(B1lds, acc0, acc1, 64, 1);     // L1
  WAITALL_BAR();
  // ---- R6 (L2) ----
  STAGE_B(B1lds, W2bT, 128, 0);
  MFMA_STEP(B0lds, acc0, acc1, 128, 1);    // L2
  WAITALL_BAR();
  // ---- R7 (softmax + T0) ----
  STAGE_B(B0lds, W2bT, 128, 64);
  SOFTMAX(acc0, 0);                        // A2 over A1: same-wave rows only
  SOFTMAX(acc1, 64);
  f32x4 accT0[8], accT1[8];
  #pragma unroll
  for (int cj = 0; cj < 8; ++cj) {
    accT0[cj] = (f32x4){0.f, 0.f, 0.f, 0.f};
    accT1[cj] = (f32x4){0.f, 0.f, 0.f, 0.f};
  }
  MFMA_STEP(B1lds, accT0, accT1, 0, 0);    // T0 (A2 same-wave, in-order DS)
  WAITALL_BAR();
  // ---- R8 (T1 + epilogue) ----
  MFMA_STEP(B0lds, accT0, accT1, 64, 0);   // T1
  // ho = xin(f32 regs)*t1 + t2 ; bounce both tiles via B1lds (free since R7)
  #pragma unroll
  for (int cj = 0; cj < 4; ++cj) {
    #pragma unroll
    for (int r = 0; r < 4; ++r) {
      int row = w * 16 + lk * 4 + r;
      int p = cj * 16 + lr;
      float hov0 = acc_x0[cj][r] * accT0[cj][r] + accT0[cj + 4][r];
      ((ushort_t*)B1lds)[row * 64 + p] = f2bf(hov0);
      float hov1 = acc_x1[cj][r] * accT1[cj][r] + accT1[cj + 4][r];
      ((ushort_t*)B1lds)[(64 + row) * 64 + p] = f2bf(hov1);
    }
  }
  asm volatile("s_waitcnt lgkmcnt(0)" ::: "memory");
  SCHED(); BAR(); SCHED();
  #pragma unroll
  for (int i = 0; i < 4; ++i) {
    int q = i * 256 + t;
    int row = q >> 3, s = q & 7;
    uint4 v = *(const uint4*)((const char*)B1lds + row * 128 + s * 16);
    *(uint4*)(ho2 + ((size_t)h * NROWS + n0 + row) * 64 + s * 8) = v;
  }
#undef STAGE_B
#undef STAGE_BX
#undef MFMA_STEP
#undef MFMAX
#undef BAR
#undef SCHED
#undef WAITALL_BAR
#undef LOAD_X
#undef CVT_AX
#undef SOFTMAX
}

// ---------------------------------------------------------------------------
extern "C" void kernel_launch(void* const* d_in, const int* in_sizes, int n_in,
                              void* d_out, int out_size, void* d_ws, size_t ws_size,
                              hipStream_t stream) {
  (void)in_sizes; (void)n_in; (void)out_size; (void)ws_size;
  const float* x    = (const float*)d_in[0];
  const float* ctrs = (const float*)d_in[1];
  const float* Wv   = (const float*)d_in[2];
  const float* Ov   = (const float*)d_in[3];
  const float* Wq   = (const float*)d_in[4];
  const float* Wo   = (const float*)d_in[5];
  float* out = (float*)d_out;

  char* wsb = (char*)d_ws;
  ushort_t* wcvtT = (ushort_t*)wsb;                   // [0, 524288)
  ushort_t* ctr3T = (ushort_t*)(wsb + 524288);        // [524288, 917504)
  float*    cb    = (float*)   (wsb + 917504);        // [917504, 921600)
  ushort_t* W2bT  = (ushort_t*)(wsb + 921600);        // [921600, 1183744)
  ushort_t* WoT   = (ushort_t*)(wsb + 1183744);       // [1183744, 1445888)
  ushort_t* ho2   = (ushort_t*)(wsb + 2097152);       // [2 MiB, 2 MiB + 8 MiB)

  prep_kernel<<<544, 256, 0, stream>>>(Wq, ctrs, Wo, Wv, Ov,
                                       wcvtT, ctr3T, cb, WoT, W2bT);
  fused_pair_kernel<<<512, 256, 0, stream>>>(x, wcvtT, ctr3T, cb, W2bT, ho2);
  gemm2_kernel<<<1024, 256, 0, stream>>>(ho2, WoT, out);
}

// Round 18
// 39.860 us; speedup vs baseline: 1.0516x; 1.0516x over previous
//
#include <hip/hip_runtime.h>
#include <math.h>

#define NROWS 8192
#define DIN   256
#define NH    8
#define NC    128
#define DOUT  256

typedef unsigned short ushort_t;
typedef __attribute__((ext_vector_type(8))) short bf16x8;
typedef __attribute__((ext_vector_type(4))) float f32x4;
typedef __attribute__((ext_vector_type(8))) unsigned short u16x8;

static __device__ __forceinline__ ushort_t f2bf(float f) {
  union { float f; unsigned u; } v; v.f = f;
  unsigned r = v.u + 0x7fffu + ((v.u >> 16) & 1u);
  return (ushort_t)(r >> 16);
}
static __device__ __forceinline__ float bf2f(ushort_t h) {
  union { unsigned u; float f; } v; v.u = ((unsigned)h) << 16;
  return v.f;
}

#define MFMA16(a, b, c) __builtin_amdgcn_mfma_f32_16x16x32_bf16((a), (b), (c), 0, 0, 0)
#define GLOAD_LDS16(g, l)                                                     \
  __builtin_amdgcn_global_load_lds(                                           \
      (const __attribute__((address_space(1))) void*)(g),                     \
      (__attribute__((address_space(3))) void*)(l), 16, 0, 0)

// ---------------------------------------------------------------------------
// Merged prep — byte-identical to r15 (best measured).
// ---------------------------------------------------------------------------
__global__ __launch_bounds__(256) void prep_kernel(
    const float* __restrict__ Wq, const float* __restrict__ ctrs,
    const float* __restrict__ Wo, const float* __restrict__ Wv,
    const float* __restrict__ Ov, ushort_t* __restrict__ wcvtT,
    ushort_t* __restrict__ ctr3T, float* __restrict__ cbias,
    ushort_t* __restrict__ WoT, ushort_t* __restrict__ W2bT) {
  int bid = blockIdx.x;
  int t = threadIdx.x;
  if (bid < 512) {
    int j = bid, k = t;
    int h = j >> 6, p = j & 63;
    float v = Wq[((size_t)k * 64 + p) * 8 + h];
    ushort_t hi = f2bf(v), lo = f2bf(v - bf2f(hi));
    wcvtT[(size_t)j * 512 + k]       = hi;
    wcvtT[(size_t)j * 512 + 256 + k] = lo;
  } else if (bid < 768) {
    int idx = (bid - 512) * 4 + (t >> 6);   // h*128+c
    int p = t & 63;
    float v = ctrs[(size_t)idx * 64 + p];
    float sq = v * v;
    #pragma unroll
    for (int off = 32; off >= 1; off >>= 1) sq += __shfl_xor(sq, off, 64);
    if (p == 0) cbias[idx] = -sq;
    ushort_t hi = f2bf(v), lo = f2bf(v - bf2f(hi));
    ctr3T[(size_t)idx * 192 + p]       = hi;
    ctr3T[(size_t)idx * 192 + 64 + p]  = lo;
    ctr3T[(size_t)idx * 192 + 128 + p] = hi;
  } else if (bid < 1280) {
    int k = bid - 768;    // 0..511
    int n = t;            // 0..255
    WoT[(size_t)n * 512 + k] = f2bf(Wo[(size_t)k * 256 + n]);
  } else {
    int b = (bid - 1280) * 4 + (t >> 6);   // h*128 + c
    int p = t & 63;
    int h = b >> 7, c = b & 127;
    const float* wv = Wv + (size_t)b * 4096;
    float acc = 0.f;
    #pragma unroll 16
    for (int g = 0; g < 64; ++g) acc += wv[g * 64 + p];
    W2bT[((size_t)h * 128 + p) * 128 + c]      = f2bf(acc);
    W2bT[((size_t)h * 128 + 64 + p) * 128 + c] = f2bf(Ov[(size_t)b * 64 + p]);
  }
}

// ---------------------------------------------------------------------------
// gemm2 — byte-identical to r15 (BM=32, 1024 blocks, 4/CU).
// ---------------------------------------------------------------------------
__global__ __launch_bounds__(256) void gemm2_kernel(
    const ushort_t* __restrict__ A, const ushort_t* __restrict__ Bt,
    float* __restrict__ out) {
  __shared__ ushort_t At[32 * 64];
  __shared__ ushort_t Bl[64 * 64];
  const int t = threadIdx.x;
  const int w = t >> 6, l = t & 63;
  const int wr = w >> 1, wc = w & 1;
  const int m0 = (blockIdx.x >> 2) * 32, n0 = (blockIdx.x & 3) * 64;
  const int lr = l & 15, lk = l >> 4;

  f32x4 acc[2];
  #pragma unroll
  for (int b = 0; b < 2; ++b) acc[b] = (f32x4){0.f, 0.f, 0.f, 0.f};

  for (int k0 = 0; k0 < 512; k0 += 64) {
    {
      int q = w * 64 + l;
      int row = q >> 3, s = q & 7;
      int kl = k0 + ((s ^ (row & 7)) << 3);
      GLOAD_LDS16(A + (size_t)(m0 + row) * 512 + kl,
                  (char*)At + (size_t)w * 1024);
    }
    #pragma unroll
    for (int i = 0; i < 2; ++i) {
      int q = (i * 4 + w) * 64 + l;
      int row = q >> 3, s = q & 7;
      int kl = k0 + ((s ^ (row & 7)) << 3);
      GLOAD_LDS16(Bt + (size_t)(n0 + row) * 512 + kl,
                  (char*)Bl + (size_t)(i * 4 + w) * 1024);
    }
    __syncthreads();
    #pragma unroll
    for (int kk = 0; kk < 2; ++kk) {
      int rowa = wr * 16 + lr;
      int sa = (kk * 4 + lk) ^ (rowa & 7);
      bf16x8 af = *(const bf16x8*)((const char*)At + rowa * 128 + sa * 16);
      #pragma unroll
      for (int b = 0; b < 2; ++b) {
        int row = wc * 32 + b * 16 + lr;
        int s = (kk * 4 + lk) ^ (row & 7);
        bf16x8 bfr = *(const bf16x8*)((const char*)Bl + row * 128 + s * 16);
        acc[b] = MFMA16(af, bfr, acc[b]);
      }
    }
    __syncthreads();
  }
  #pragma unroll
  for (int b = 0; b < 2; ++b) {
    #pragma unroll
    for (int r = 0; r < 4; ++r) {
      int rowg = m0 + wr * 16 + lk * 4 + r;
      int colg = n0 + wc * 32 + b * 16 + lr;
      out[(size_t)rowg * 256 + colg] = acc[b][r];
    }
  }
}

// ---------------------------------------------------------------------------
// Fused-pair v5 (8 waves / 512 threads): 128-token tile, wave w owns the
// 16-row band [16w, 16w+16). Same 10-region schedule and per-element MFMA
// order as r15 -> bit-identical output. LDS unchanged (70.1 KB, 2 blocks/CU)
// but 16 waves/CU (was 8); per-wave payload and VGPR halve
// (__launch_bounds__(512,4) caps at 128 VGPR).
// ---------------------------------------------------------------------------
__global__ __launch_bounds__(512, 4) void fused_pair_kernel(
    const float* __restrict__ x,          // [8192][256] f32
    const ushort_t* __restrict__ wcvtT,   // [512][512] hi|lo
    const ushort_t* __restrict__ ctr3T,   // [1024][192]
    const float* __restrict__ cbias,      // [1024]
    const ushort_t* __restrict__ W2bT,    // [1024][128]
    ushort_t* __restrict__ ho2) {         // flat (h,N,p)
  __shared__ __align__(16) char Au_raw[36864];
  __shared__ char B0lds[16384];
  __shared__ char B1lds[16384];
  __shared__ float cb_lds[128];

  ushort_t* Axh = (ushort_t*)Au_raw;             // [128][72]
  ushort_t* Axl = (ushort_t*)(Au_raw + 18432);   // [128][72]
  ushort_t* A1  = (ushort_t*)Au_raw;             // [128][136]
  ushort_t* A2  = (ushort_t*)Au_raw;             // [128][136]

  const int t = threadIdx.x;
  const int w = t >> 6, l = t & 63;              // w in 0..7
  const int lr = l & 15, lk = l >> 4;
  const int h = blockIdx.x >> 6;                 // 8 heads x 64 pairs
  const int n0 = (blockIdx.x & 63) * 128;

#define STAGE_B(BUF, SRC, LDB, KOFF)                                          \
  {                                                                           \
    _Pragma("unroll")                                                         \
    for (int i = 0; i < 2; ++i) {                                             \
      int q = (i * 8 + w) * 64 + l;                                           \
      int row = q >> 3, s = q & 7;                                            \
      GLOAD_LDS16((SRC) + (size_t)(h * 128 + row) * (LDB) + (KOFF) +          \
                      ((s ^ (row & 7)) << 3),                                 \
                  (char*)(BUF) + (size_t)(i * 8 + w) * 1024);                 \
    }                                                                         \
  }

#define STAGE_BX(BUF, KC)                                                     \
  {                                                                           \
    _Pragma("unroll")                                                         \
    for (int i = 0; i < 2; ++i) {                                             \
      int q = (i * 8 + w) * 64 + l;                                           \
      int row = q >> 3, s = q & 7;                                            \
      int sw = (s ^ (row & 7)) << 3;                                          \
      int jj = h * 64 + (row & 63);                                           \
      int koff = (row < 64 ? 0 : 256) + (KC) * 64 + sw;                       \
      GLOAD_LDS16(wcvtT + (size_t)jj * 512 + koff,                            \
                  (char*)(BUF) + (size_t)(i * 8 + w) * 1024);                 \
    }                                                                         \
  }

#define MFMA_STEP(BUF, ACC, KBASE, ASPLIT)                                    \
  {                                                                           \
    _Pragma("unroll")                                                         \
    for (int kk = 0; kk < 2; ++kk) {                                          \
      int klog = (KBASE) + kk * 32 + lk * 8;                                  \
      int kp = (ASPLIT) ? (klog < 64 ? klog : klog - 64) : klog;              \
      bf16x8 af = *(const bf16x8*)&A1[(w * 16 + lr) * 136 + kp];              \
      _Pragma("unroll")                                                       \
      for (int cj = 0; cj < 8; ++cj) {                                        \
        int brow = cj * 16 + lr;                                              \
        int slot = (kk * 4 + lk) ^ (brow & 7);                                \
        bf16x8 bfr =                                                          \
            *(const bf16x8*)((const char*)(BUF) + brow * 128 + slot * 16);    \
        (ACC)[cj] = MFMA16(af, bfr, (ACC)[cj]);                               \
      }                                                                       \
    }                                                                         \
  }

#define MFMAX(BUF)                                                            \
  {                                                                           \
    _Pragma("unroll")                                                         \
    for (int kk = 0; kk < 2; ++kk) {                                          \
      bf16x8 ah = *(const bf16x8*)&Axh[(w * 16 + lr) * 72 + kk * 32 + lk * 8];\
      bf16x8 al = *(const bf16x8*)&Axl[(w * 16 + lr) * 72 + kk * 32 + lk * 8];\
      _Pragma("unroll")                                                       \
      for (int cj = 0; cj < 4; ++cj) {                                        \
        int rh = cj * 16 + lr;                                                \
        int slot = (kk * 4 + lk) ^ (rh & 7);                                  \
        bf16x8 bh = *(const bf16x8*)((const char*)(BUF) + rh * 128 + slot * 16);\
        bf16x8 bl = *(const bf16x8*)((const char*)(BUF) + (64 + rh) * 128 + slot * 16);\
        acc_x[cj] = MFMA16(ah, bh, acc_x[cj]);                                \
        acc_x[cj] = MFMA16(al, bh, acc_x[cj]);                                \
        acc_x[cj] = MFMA16(ah, bl, acc_x[cj]);                                \
      }                                                                       \
    }                                                                         \
  }

#define BAR() __builtin_amdgcn_s_barrier()
#define SCHED() __builtin_amdgcn_sched_barrier(0)
#define WAITALL_BAR()                                                         \
  {                                                                           \
    asm volatile("s_waitcnt vmcnt(0) lgkmcnt(0)" ::: "memory");               \
    SCHED(); BAR(); SCHED();                                                  \
  }

  const int xrow = t >> 2;                 // 0..127 (wave w: rows 16w..16w+15)
  const int xseg = (t & 3) << 4;           // 0/16/32/48
  const float* xb = x + (size_t)(n0 + xrow) * 256 + xseg;
  float4 xr[4];

#define LOAD_X(KC)                                                            \
  {                                                                           \
    _Pragma("unroll")                                                         \
    for (int j = 0; j < 4; ++j) xr[j] = *(const float4*)(xb + (KC) * 64 + j * 4); \
  }

#define CVT_AX()                                                              \
  {                                                                           \
    u16x8 hv0, hv1, lv0, lv1;                                                 \
    _Pragma("unroll")                                                         \
    for (int j = 0; j < 2; ++j) {                                             \
      float f4[8] = {xr[j*2].x, xr[j*2].y, xr[j*2].z, xr[j*2].w,              \
                     xr[j*2+1].x, xr[j*2+1].y, xr[j*2+1].z, xr[j*2+1].w};     \
      _Pragma("unroll")                                                       \
      for (int e = 0; e < 8; ++e) {                                           \
        ushort_t hi = f2bf(f4[e]);                                            \
        if (j == 0) { hv0[e] = hi; lv0[e] = f2bf(f4[e] - bf2f(hi)); }         \
        else        { hv1[e] = hi; lv1[e] = f2bf(f4[e] - bf2f(hi)); }         \
      }                                                                       \
    }                                                                         \
    *(u16x8*)&Axh[xrow * 72 + xseg]     = hv0;                                \
    *(u16x8*)&Axh[xrow * 72 + xseg + 8] = hv1;                                \
    *(u16x8*)&Axl[xrow * 72 + xseg]     = lv0;                                \
    *(u16x8*)&Axl[xrow * 72 + xseg + 8] = lv1;                                \
  }

#define SOFTMAX(ACC)                                                          \
  {                                                                           \
    float cbv[8];                                                             \
    _Pragma("unroll")                                                         \
    for (int cj = 0; cj < 8; ++cj) cbv[cj] = cb_lds[cj * 16 + lr];            \
    _Pragma("unroll")                                                         \
    for (int r = 0; r < 4; ++r) {                                             \
      float v[8];                                                             \
      float m = -1e30f;                                                       \
      _Pragma("unroll")                                                       \
      for (int cj = 0; cj < 8; ++cj) {                                        \
        v[cj] = 2.f * (ACC)[cj][r] + cbv[cj];                                 \
        m = fmaxf(m, v[cj]);                                                  \
      }                                                                       \
      m = fmaxf(m, __shfl_xor(m, 1, 64));                                     \
      m = fmaxf(m, __shfl_xor(m, 2, 64));                                     \
      m = fmaxf(m, __shfl_xor(m, 4, 64));                                     \
      m = fmaxf(m, __shfl_xor(m, 8, 64));                                     \
      float s = 0.f;                                                          \
      _Pragma("unroll")                                                       \
      for (int cj = 0; cj < 8; ++cj) {                                        \
        v[cj] = __expf(v[cj] - m);                                            \
        s += v[cj];                                                           \
      }                                                                       \
      s += __shfl_xor(s, 1, 64);                                              \
      s += __shfl_xor(s, 2, 64);                                              \
      s += __shfl_xor(s, 4, 64);                                              \
      s += __shfl_xor(s, 8, 64);                                              \
      float inv = 1.f / s;                                                    \
      int row = w * 16 + lk * 4 + r;                                          \
      _Pragma("unroll")                                                       \
      for (int cj = 0; cj < 8; ++cj)                                          \
        A2[row * 136 + cj * 16 + lr] = f2bf(v[cj] * inv);                     \
    }                                                                         \
  }

  // ---- Prologue: stage B(chunk0); x0 -> Ax ----
  cb_lds[t & 127] = cbias[h * 128 + (t & 127)];
  STAGE_BX(B0lds, 0);
  LOAD_X(0);
  f32x4 acc_x[4];
  #pragma unroll
  for (int cj = 0; cj < 4; ++cj) acc_x[cj] = (f32x4){0.f, 0.f, 0.f, 0.f};
  CVT_AX();                                // chunk0 -> Ax (wave-local band)
  WAITALL_BAR();                           // B0 ready

  // ---- R0 (chunk 0) ----
  STAGE_BX(B1lds, 1);
  LOAD_X(1);
  MFMAX(B0lds);
  CVT_AX();
  WAITALL_BAR();
  // ---- R1 (chunk 1) ----
  STAGE_BX(B0lds, 2);
  LOAD_X(2);
  MFMAX(B1lds);
  CVT_AX();
  WAITALL_BAR();
  // ---- R2 (chunk 2) ----
  STAGE_BX(B1lds, 3);
  LOAD_X(3);
  MFMAX(B0lds);
  CVT_AX();
  WAITALL_BAR();
  // ---- R3 (chunk 3) ----
  STAGE_B(B0lds, ctr3T, 192, 0);
  MFMAX(B1lds);
  WAITALL_BAR();                           // Ax dead for ALL waves after this

  // ---- R4 (L0): write A1 from acc_x (wave-local band), logits k 0..63 ----
  STAGE_B(B1lds, ctr3T, 192, 64);
  #pragma unroll
  for (int cj = 0; cj < 4; ++cj) {
    #pragma unroll
    for (int r = 0; r < 4; ++r) {
      int row = w * 16 + lk * 4 + r;
      int p = cj * 16 + lr;
      float v0 = acc_x[cj][r];
      ushort_t hi0 = f2bf(v0);
      A1[row * 136 + p] = hi0;
      A1[row * 136 + 64 + p] = f2bf(v0 - bf2f(hi0));
    }
  }
  f32x4 acc[8];
  #pragma unroll
  for (int cj = 0; cj < 8; ++cj) acc[cj] = (f32x4){0.f, 0.f, 0.f, 0.f};
  MFMA_STEP(B0lds, acc, 0, 1);             // L0 (A1 same-wave, in-order DS)
  WAITALL_BAR();
  // ---- R5 (L1) ----
  STAGE_B(B0lds, ctr3T, 192, 128);
  MFMA_STEP(B1lds, acc, 64, 1);            // L1
  WAITALL_BAR();
  // ---- R6 (L2) ----
  STAGE_B(B1lds, W2bT, 128, 0);
  MFMA_STEP(B0lds, acc, 128, 1);           // L2
  WAITALL_BAR();
  // ---- R7 (softmax + T0) ----
  STAGE_B(B0lds, W2bT, 128, 64);
  SOFTMAX(acc);                            // A2 over A1: same-wave band only
  f32x4 accT[8];
  #pragma unroll
  for (int cj = 0; cj < 8; ++cj) accT[cj] = (f32x4){0.f, 0.f, 0.f, 0.f};
  MFMA_STEP(B1lds, accT, 0, 0);            // T0 (A2 same-wave, in-order DS)
  WAITALL_BAR();
  // ---- R8 (T1 + epilogue) ----
  MFMA_STEP(B0lds, accT, 64, 0);           // T1
  #pragma unroll
  for (int cj = 0; cj < 4; ++cj) {
    #pragma unroll
    for (int r = 0; r < 4; ++r) {
      int row = w * 16 + lk * 4 + r;
      int p = cj * 16 + lr;
      float hov = acc_x[cj][r] * accT[cj][r] + accT[cj + 4][r];
      ((ushort_t*)B1lds)[row * 64 + p] = f2bf(hov);
    }
  }
  asm volatile("s_waitcnt lgkmcnt(0)" ::: "memory");
  SCHED(); BAR(); SCHED();
  #pragma unroll
  for (int i = 0; i < 2; ++i) {
    int q = i * 512 + t;
    int row = q >> 3, s = q & 7;
    uint4 v = *(const uint4*)((const char*)B1lds + row * 128 + s * 16);
    *(uint4*)(ho2 + ((size_t)h * NROWS + n0 + row) * 64 + s * 8) = v;
  }
#undef STAGE_B
#undef STAGE_BX
#undef MFMA_STEP
#undef MFMAX
#undef BAR
#undef SCHED
#undef WAITALL_BAR
#undef LOAD_X
#undef CVT_AX
#undef SOFTMAX
}

// ---------------------------------------------------------------------------
extern "C" void kernel_launch(void* const* d_in, const int* in_sizes, int n_in,
                              void* d_out, int out_size, void* d_ws, size_t ws_size,
                              hipStream_t stream) {
  (void)in_sizes; (void)n_in; (void)out_size; (void)ws_size;
  const float* x    = (const float*)d_in[0];
  const float* ctrs = (const float*)d_in[1];
  const float* Wv   = (const float*)d_in[2];
  const float* Ov   = (const float*)d_in[3];
  const float* Wq   = (const float*)d_in[4];
  const float* Wo   = (const float*)d_in[5];
  float* out = (float*)d_out;

  char* wsb = (char*)d_ws;
  ushort_t* wcvtT = (ushort_t*)wsb;                   // [0, 524288)
  ushort_t* ctr3T = (ushort_t*)(wsb + 524288);        // [524288, 917504)
  float*    cb    = (float*)   (wsb + 917504);        // [917504, 921600)
  ushort_t* W2bT  = (ushort_t*)(wsb + 921600);        // [921600, 1183744)
  ushort_t* WoT   = (ushort_t*)(wsb + 1183744);       // [1183744, 1445888)
  ushort_t* ho2   = (ushort_t*)(wsb + 2097152);       // [2 MiB, 2 MiB + 8 MiB)

  prep_kernel<<<1536, 256, 0, stream>>>(Wq, ctrs, Wo, Wv, Ov,
                                        wcvtT, ctr3T, cb, WoT, W2bT);
  fused_pair_kernel<<<512, 512, 0, stream>>>(x, wcvtT, ctr3T, cb, W2bT, ho2);
  gemm2_kernel<<<1024, 256, 0, stream>>>(ho2, WoT, out);
}

// Round 19
// 35.276 us; speedup vs baseline: 1.1883x; 1.1300x over previous
//
#include <hip/hip_runtime.h>
#include <math.h>

#define NROWS 8192
#define DIN   256
#define NH    8
#define NC    128
#define DOUT  256

typedef unsigned short ushort_t;
typedef __attribute__((ext_vector_type(8))) short bf16x8;
typedef __attribute__((ext_vector_type(8))) _Float16 f16x8;
typedef __attribute__((ext_vector_type(4))) float f32x4;

static __device__ __forceinline__ ushort_t f2bf(float f) {
  union { float f; unsigned u; } v; v.f = f;
  unsigned r = v.u + 0x7fffu + ((v.u >> 16) & 1u);
  return (ushort_t)(r >> 16);
}
static __device__ __forceinline__ float bf2f(ushort_t h) {
  union { unsigned u; float f; } v; v.u = ((unsigned)h) << 16;
  return v.f;
}

#define MFMA16(a, b, c) __builtin_amdgcn_mfma_f32_16x16x32_bf16((a), (b), (c), 0, 0, 0)
#define MFMA16F(a, b, c) __builtin_amdgcn_mfma_f32_16x16x32_f16((a), (b), (c), 0, 0, 0)
#define GLOAD_LDS16(g, l)                                                     \
  __builtin_amdgcn_global_load_lds(                                           \
      (const __attribute__((address_space(1))) void*)(g),                     \
      (__attribute__((address_space(3))) void*)(l), 16, 0, 0)

// ---------------------------------------------------------------------------
// Merged prep (grid 1536 x 256):
//  [0,512):    Wq -> wq16 f16 [j=h*64+p][256]
//  [512,768):  ctrs -> ctr16 f16 [h*128+c][64] + cbias
//  [768,1280): Wo -> WoT bf16 [n][512]
//  [1280,1536): Wv/Ov -> W2bT bf16 [h*128+n][128]
// ---------------------------------------------------------------------------
__global__ __launch_bounds__(256) void prep_kernel(
    const float* __restrict__ Wq, const float* __restrict__ ctrs,
    const float* __restrict__ Wo, const float* __restrict__ Wv,
    const float* __restrict__ Ov, _Float16* __restrict__ wq16,
    _Float16* __restrict__ ctr16, float* __restrict__ cbias,
    ushort_t* __restrict__ WoT, ushort_t* __restrict__ W2bT) {
  int bid = blockIdx.x;
  int t = threadIdx.x;
  if (bid < 512) {
    int j = bid, k = t;
    int h = j >> 6, p = j & 63;
    float v = Wq[((size_t)k * 64 + p) * 8 + h];
    wq16[(size_t)j * 256 + k] = (_Float16)v;
  } else if (bid < 768) {
    int idx = (bid - 512) * 4 + (t >> 6);   // h*128+c
    int p = t & 63;
    float v = ctrs[(size_t)idx * 64 + p];
    float sq = v * v;
    #pragma unroll
    for (int off = 32; off >= 1; off >>= 1) sq += __shfl_xor(sq, off, 64);
    if (p == 0) cbias[idx] = -sq;
    ctr16[(size_t)idx * 64 + p] = (_Float16)v;
  } else if (bid < 1280) {
    int k = bid - 768;    // 0..511
    int n = t;            // 0..255
    WoT[(size_t)n * 512 + k] = f2bf(Wo[(size_t)k * 256 + n]);
  } else {
    int b = (bid - 1280) * 4 + (t >> 6);   // h*128 + c
    int p = t & 63;
    int h = b >> 7, c = b & 127;
    const float* wv = Wv + (size_t)b * 4096;
    float acc = 0.f;
    #pragma unroll 16
    for (int g = 0; g < 64; ++g) acc += wv[g * 64 + p];
    W2bT[((size_t)h * 128 + p) * 128 + c]      = f2bf(acc);
    W2bT[((size_t)h * 128 + 64 + p) * 128 + c] = f2bf(Ov[(size_t)b * 64 + p]);
  }
}

// ---------------------------------------------------------------------------
// gemm2 — byte-identical to r15/r18 (BM=32, 1024 blocks, 4/CU).
// ---------------------------------------------------------------------------
__global__ __launch_bounds__(256) void gemm2_kernel(
    const ushort_t* __restrict__ A, const ushort_t* __restrict__ Bt,
    float* __restrict__ out) {
  __shared__ ushort_t At[32 * 64];
  __shared__ ushort_t Bl[64 * 64];
  const int t = threadIdx.x;
  const int w = t >> 6, l = t & 63;
  const int wr = w >> 1, wc = w & 1;
  const int m0 = (blockIdx.x >> 2) * 32, n0 = (blockIdx.x & 3) * 64;
  const int lr = l & 15, lk = l >> 4;

  f32x4 acc[2];
  #pragma unroll
  for (int b = 0; b < 2; ++b) acc[b] = (f32x4){0.f, 0.f, 0.f, 0.f};

  for (int k0 = 0; k0 < 512; k0 += 64) {
    {
      int q = w * 64 + l;
      int row = q >> 3, s = q & 7;
      int kl = k0 + ((s ^ (row & 7)) << 3);
      GLOAD_LDS16(A + (size_t)(m0 + row) * 512 + kl,
                  (char*)At + (size_t)w * 1024);
    }
    #pragma unroll
    for (int i = 0; i < 2; ++i) {
      int q = (i * 4 + w) * 64 + l;
      int row = q >> 3, s = q & 7;
      int kl = k0 + ((s ^ (row & 7)) << 3);
      GLOAD_LDS16(Bt + (size_t)(n0 + row) * 512 + kl,
                  (char*)Bl + (size_t)(i * 4 + w) * 1024);
    }
    __syncthreads();
    #pragma unroll
    for (int kk = 0; kk < 2; ++kk) {
      int rowa = wr * 16 + lr;
      int sa = (kk * 4 + lk) ^ (rowa & 7);
      bf16x8 af = *(const bf16x8*)((const char*)At + rowa * 128 + sa * 16);
      #pragma unroll
      for (int b = 0; b < 2; ++b) {
        int row = wc * 32 + b * 16 + lr;
        int s = (kk * 4 + lk) ^ (row & 7);
        bf16x8 bfr = *(const bf16x8*)((const char*)Bl + row * 128 + s * 16);
        acc[b] = MFMA16(af, bfr, acc[b]);
      }
    }
    __syncthreads();
  }
  #pragma unroll
  for (int b = 0; b < 2; ++b) {
    #pragma unroll
    for (int r = 0; r < 4; ++r) {
      int rowg = m0 + wr * 16 + lk * 4 + r;
      int colg = n0 + wc * 32 + b * 16 + lr;
      out[(size_t)rowg * 256 + colg] = acc[b][r];
    }
  }
}

// ---------------------------------------------------------------------------
// Fused-pair v6 (f16 front-end): 8 waves / 512 thr, 128-token tile, wave w
// owns rows [16w,16w+16). Phases: xin = x@Wq in f16 (K=256, 2 double-chunk
// regions) -> logits = xin.ctr in f16 (K=64, 1 region) -> softmax -> T =
// a@W2 bf16 (2 regions) -> ho -> FLAT (h,N,p). One A-buffer [128][136]x2B
// reused as Ax(f16,128c) -> A1(f16,64c) -> A2(bf16,128c); all wave-private
// bands with identical byte ranges per band across views. 6 barriers.
// LDS 67.3 KB -> 2 blocks/CU, 16 waves/CU.
// ---------------------------------------------------------------------------
__global__ __launch_bounds__(512, 4) void fused_pair_kernel(
    const float* __restrict__ x,          // [8192][256] f32
    const _Float16* __restrict__ wq16,    // [512][256]
    const _Float16* __restrict__ ctr16,   // [1024][64]
    const float* __restrict__ cbias,      // [1024]
    const ushort_t* __restrict__ W2bT,    // [1024][128]
    ushort_t* __restrict__ ho2) {         // flat (h,N,p)
  __shared__ __align__(16) char Au_raw[34816];   // [128][136] x 2B
  __shared__ char B0lds[16384];
  __shared__ char B1lds[16384];
  __shared__ float cb_lds[128];

  _Float16* Axf = (_Float16*)Au_raw;             // [128][136] (cols 0..127)
  _Float16* A1f = (_Float16*)Au_raw;             // [128][136] (cols 0..63)
  ushort_t* A2  = (ushort_t*)Au_raw;             // [128][136] (cols 0..127)

  const int t = threadIdx.x;
  const int w = t >> 6, l = t & 63;              // w in 0..7
  const int lr = l & 15, lk = l >> 4;
  const int h = blockIdx.x >> 6;                 // 8 heads x 64 pairs
  const int n0 = (blockIdx.x & 63) * 128;

  // stage Wq double-chunk (64 j-rows x 128 k f16 = 16KB; row stride 256B)
#define STAGE_WQ2(BUF, KC2)                                                   \
  {                                                                           \
    _Pragma("unroll")                                                         \
    for (int i = 0; i < 2; ++i) {                                             \
      int q = (i * 8 + w) * 64 + l;       /* 0..1023 */                       \
      int jrow = q >> 4, s16 = q & 15;                                        \
      int c2 = s16 >> 3, s = s16 & 7;                                         \
      GLOAD_LDS16(wq16 + (size_t)(h * 64 + jrow) * 256 + (KC2) * 128 +        \
                      c2 * 64 + ((s ^ (jrow & 7)) << 3),                      \
                  (char*)(BUF) + (size_t)q * 16);                             \
    }                                                                         \
  }

  // stage 128-row x 64-col tile (16KB; row stride 128B); ELT = element bytes 2
#define STAGE_B128(BUF, SRC, LDB, KOFF)                                       \
  {                                                                           \
    _Pragma("unroll")                                                         \
    for (int i = 0; i < 2; ++i) {                                             \
      int q = (i * 8 + w) * 64 + l;       /* 0..1023 */                       \
      int row = q >> 3, s = q & 7;                                            \
      GLOAD_LDS16((SRC) + (size_t)(h * 128 + row) * (LDB) + (KOFF) +          \
                      ((s ^ (row & 7)) << 3),                                 \
                  (char*)(BUF) + (size_t)q * 16);                             \
    }                                                                         \
  }

  // xin MFMA: 2 sub-chunks x 2 kk x 4 cj, f16
#define MFMAX(BUF)                                                            \
  {                                                                           \
    _Pragma("unroll")                                                         \
    for (int c2 = 0; c2 < 2; ++c2) {                                          \
      _Pragma("unroll")                                                       \
      for (int kk = 0; kk < 2; ++kk) {                                        \
        f16x8 af = *(const f16x8*)&Axf[(w * 16 + lr) * 136 + c2 * 64 +        \
                                       kk * 32 + lk * 8];                     \
        _Pragma("unroll")                                                     \
        for (int cj = 0; cj < 4; ++cj) {                                      \
          int rh = cj * 16 + lr;                                              \
          int slot = (kk * 4 + lk) ^ (rh & 7);                                \
          f16x8 bfr = *(const f16x8*)((const char*)(BUF) + rh * 256 +         \
                                      c2 * 128 + slot * 16);                  \
          acc_x[cj] = MFMA16F(af, bfr, acc_x[cj]);                            \
        }                                                                     \
      }                                                                       \
    }                                                                         \
  }

  // logits MFMA: K=64 f16, 8 cj (128 centroids)
#define MFMA_L(BUF, ACC)                                                      \
  {                                                                           \
    _Pragma("unroll")                                                         \
    for (int kk = 0; kk < 2; ++kk) {                                          \
      f16x8 af = *(const f16x8*)&A1f[(w * 16 + lr) * 136 + kk * 32 + lk * 8]; \
      _Pragma("unroll")                                                       \
      for (int cj = 0; cj < 8; ++cj) {                                        \
        int brow = cj * 16 + lr;                                              \
        int slot = (kk * 4 + lk) ^ (brow & 7);                                \
        f16x8 bfr =                                                           \
            *(const f16x8*)((const char*)(BUF) + brow * 128 + slot * 16);     \
        (ACC)[cj] = MFMA16F(af, bfr, (ACC)[cj]);                              \
      }                                                                       \
    }                                                                         \
  }

  // T MFMA: bf16, A2 cols [KB, KB+64)
#define MFMA_T(BUF, ACC, KB)                                                  \
  {                                                                           \
    _Pragma("unroll")                                                         \
    for (int kk = 0; kk < 2; ++kk) {                                          \
      bf16x8 af = *(const bf16x8*)&A2[(w * 16 + lr) * 136 + (KB) + kk * 32 +  \
                                      lk * 8];                                \
      _Pragma("unroll")                                                       \
      for (int cj = 0; cj < 8; ++cj) {                                        \
        int brow = cj * 16 + lr;                                              \
        int slot = (kk * 4 + lk) ^ (brow & 7);                                \
        bf16x8 bfr =                                                          \
            *(const bf16x8*)((const char*)(BUF) + brow * 128 + slot * 16);    \
        (ACC)[cj] = MFMA16(af, bfr, (ACC)[cj]);                               \
      }                                                                       \
    }                                                                         \
  }

#define BAR() __builtin_amdgcn_s_barrier()
#define SCHED() __builtin_amdgcn_sched_barrier(0)
#define WAITALL_BAR()                                                         \
  {                                                                           \
    asm volatile("s_waitcnt vmcnt(0) lgkmcnt(0)" ::: "memory");               \
    SCHED(); BAR(); SCHED();                                                  \
  }

  const int xrow = t >> 2;                 // 0..127 (wave w: rows 16w..16w+15)
  const int xsegf = (t & 3) << 4;          // 0/16/32/48 (floats within chunk)
  const float* xb = x + (size_t)(n0 + xrow) * 256 + xsegf;
  float4 xr[8];

#define LOAD_X2(KC2)                                                          \
  {                                                                           \
    _Pragma("unroll")                                                         \
    for (int c2 = 0; c2 < 2; ++c2)                                            \
      _Pragma("unroll")                                                       \
      for (int j = 0; j < 4; ++j)                                             \
        xr[c2 * 4 + j] =                                                      \
            *(const float4*)(xb + (KC2) * 128 + c2 * 64 + j * 4);             \
  }

#define CVT_AX2()                                                             \
  {                                                                           \
    _Pragma("unroll")                                                         \
    for (int c2 = 0; c2 < 2; ++c2) {                                          \
      f16x8 h0, h1;                                                           \
      float f0[8] = {xr[c2*4].x,   xr[c2*4].y,   xr[c2*4].z,   xr[c2*4].w,    \
                     xr[c2*4+1].x, xr[c2*4+1].y, xr[c2*4+1].z, xr[c2*4+1].w}; \
      float f1[8] = {xr[c2*4+2].x, xr[c2*4+2].y, xr[c2*4+2].z, xr[c2*4+2].w,  \
                     xr[c2*4+3].x, xr[c2*4+3].y, xr[c2*4+3].z, xr[c2*4+3].w}; \
      _Pragma("unroll")                                                       \
      for (int e = 0; e < 8; ++e) { h0[e] = (_Float16)f0[e];                  \
                                    h1[e] = (_Float16)f1[e]; }                \
      *(f16x8*)&Axf[xrow * 136 + c2 * 64 + xsegf]     = h0;                   \
      *(f16x8*)&Axf[xrow * 136 + c2 * 64 + xsegf + 8] = h1;                   \
    }                                                                         \
  }

  // ---- Prologue ----
  cb_lds[t & 127] = cbias[h * 128 + (t & 127)];
  STAGE_WQ2(B0lds, 0);
  LOAD_X2(0);
  f32x4 acc_x[4];
  #pragma unroll
  for (int cj = 0; cj < 4; ++cj) acc_x[cj] = (f32x4){0.f, 0.f, 0.f, 0.f};
  CVT_AX2();
  WAITALL_BAR();                           // B0 (Wq chunks 0-1) ready

  // ---- R0: xin chunks 0-1; stage Wq 2-3; load/cvt x 2-3 ----
  STAGE_WQ2(B1lds, 1);
  LOAD_X2(1);
  MFMAX(B0lds);
  CVT_AX2();                               // own-band, after own reads
  WAITALL_BAR();
  // ---- R1: xin chunks 2-3; stage ctr; write A1 (f16, own band) ----
  STAGE_B128(B0lds, ctr16, 64, 0);
  MFMAX(B1lds);
  #pragma unroll
  for (int cj = 0; cj < 4; ++cj) {
    #pragma unroll
    for (int r = 0; r < 4; ++r) {
      int row = w * 16 + lk * 4 + r;
      A1f[row * 136 + cj * 16 + lr] = (_Float16)acc_x[cj][r];
    }
  }
  WAITALL_BAR();
  // ---- R2: logits + softmax; stage W2 k0 ----
  STAGE_B128(B1lds, W2bT, 128, 0);
  f32x4 acc[8];
  #pragma unroll
  for (int cj = 0; cj < 8; ++cj) acc[cj] = (f32x4){0.f, 0.f, 0.f, 0.f};
  MFMA_L(B0lds, acc);
  {
    float cbv[8];
    #pragma unroll
    for (int cj = 0; cj < 8; ++cj) cbv[cj] = cb_lds[cj * 16 + lr];
    #pragma unroll
    for (int r = 0; r < 4; ++r) {
      float v[8];
      float m = -1e30f;
      #pragma unroll
      for (int cj = 0; cj < 8; ++cj) {
        v[cj] = 2.f * acc[cj][r] + cbv[cj];
        m = fmaxf(m, v[cj]);
      }
      m = fmaxf(m, __shfl_xor(m, 1, 64));
      m = fmaxf(m, __shfl_xor(m, 2, 64));
      m = fmaxf(m, __shfl_xor(m, 4, 64));
      m = fmaxf(m, __shfl_xor(m, 8, 64));
      float s = 0.f;
      #pragma unroll
      for (int cj = 0; cj < 8; ++cj) {
        v[cj] = __expf(v[cj] - m);
        s += v[cj];
      }
      s += __shfl_xor(s, 1, 64);
      s += __shfl_xor(s, 2, 64);
      s += __shfl_xor(s, 4, 64);
      s += __shfl_xor(s, 8, 64);
      float inv = 1.f / s;
      int row = w * 16 + lk * 4 + r;
      #pragma unroll
      for (int cj = 0; cj < 8; ++cj)
        A2[row * 136 + cj * 16 + lr] = f2bf(v[cj] * inv);
    }
  }
  WAITALL_BAR();
  // ---- R3: T0; stage W2 k64 ----
  STAGE_B128(B0lds, W2bT, 128, 64);
  f32x4 accT[8];
  #pragma unroll
  for (int cj = 0; cj < 8; ++cj) accT[cj] = (f32x4){0.f, 0.f, 0.f, 0.f};
  MFMA_T(B1lds, accT, 0);
  WAITALL_BAR();
  // ---- R4: T1 + epilogue ----
  MFMA_T(B0lds, accT, 64);
  #pragma unroll
  for (int cj = 0; cj < 4; ++cj) {
    #pragma unroll
    for (int r = 0; r < 4; ++r) {
      int row = w * 16 + lk * 4 + r;
      int p = cj * 16 + lr;
      float hov = acc_x[cj][r] * accT[cj][r] + accT[cj + 4][r];
      ((ushort_t*)B1lds)[row * 64 + p] = f2bf(hov);
    }
  }
  asm volatile("s_waitcnt lgkmcnt(0)" ::: "memory");
  SCHED(); BAR(); SCHED();
  #pragma unroll
  for (int i = 0; i < 2; ++i) {
    int q = i * 512 + t;
    int row = q >> 3, s = q & 7;
    uint4 v = *(const uint4*)((const char*)B1lds + row * 128 + s * 16);
    *(uint4*)(ho2 + ((size_t)h * NROWS + n0 + row) * 64 + s * 8) = v;
  }
#undef STAGE_WQ2
#undef STAGE_B128
#undef MFMAX
#undef MFMA_L
#undef MFMA_T
#undef BAR
#undef SCHED
#undef WAITALL_BAR
#undef LOAD_X2
#undef CVT_AX2
}

// ---------------------------------------------------------------------------
extern "C" void kernel_launch(void* const* d_in, const int* in_sizes, int n_in,
                              void* d_out, int out_size, void* d_ws, size_t ws_size,
                              hipStream_t stream) {
  (void)in_sizes; (void)n_in; (void)out_size; (void)ws_size;
  const float* x    = (const float*)d_in[0];
  const float* ctrs = (const float*)d_in[1];
  const float* Wv   = (const float*)d_in[2];
  const float* Ov   = (const float*)d_in[3];
  const float* Wq   = (const float*)d_in[4];
  const float* Wo   = (const float*)d_in[5];
  float* out = (float*)d_out;

  char* wsb = (char*)d_ws;
  _Float16* wq16  = (_Float16*)wsb;                   // [0, 262144)
  _Float16* ctr16 = (_Float16*)(wsb + 262144);        // [262144, 393216)
  float*    cb    = (float*)   (wsb + 393216);        // [393216, 397312)
  ushort_t* W2bT  = (ushort_t*)(wsb + 397312);        // [397312, 659456)
  ushort_t* WoT   = (ushort_t*)(wsb + 659456);        // [659456, 921600)
  ushort_t* ho2   = (ushort_t*)(wsb + 2097152);       // [2 MiB, 2 MiB + 8 MiB)

  prep_kernel<<<1536, 256, 0, stream>>>(Wq, ctrs, Wo, Wv, Ov,
                                        wq16, ctr16, cb, WoT, W2bT);
  fused_pair_kernel<<<512, 512, 0, stream>>>(x, wq16, ctr16, cb, W2bT, ho2);
  gemm2_kernel<<<1024, 256, 0, stream>>>(ho2, WoT, out);
}